// Round 5
// baseline (269.531 us; speedup 1.0000x reference)
//
#include <hip/hip_runtime.h>

typedef float f32x4 __attribute__((ext_vector_type(4)));
typedef __bf16 bf16x8 __attribute__((ext_vector_type(8)));
typedef __bf16 bf16x4 __attribute__((ext_vector_type(4)));
typedef int i32x4 __attribute__((ext_vector_type(4)));

// XOR swizzle in elements (2B): byte ^= ((row&7)<<4)  ->  elem col ^= ((row&7)<<3)
__device__ __forceinline__ int swz(int row, int col) {
  return col ^ ((row & 7) << 3);
}

__device__ __forceinline__ bf16x8 cvt8(const float* __restrict__ src) {
  f32x4 a = *(const f32x4*)src;
  f32x4 b = *(const f32x4*)(src + 4);
  bf16x8 r;
  r[0] = (__bf16)a[0]; r[1] = (__bf16)a[1]; r[2] = (__bf16)a[2]; r[3] = (__bf16)a[3];
  r[4] = (__bf16)b[0]; r[5] = (__bf16)b[1]; r[6] = (__bf16)b[2]; r[7] = (__bf16)b[3];
  return r;
}

__device__ __forceinline__ bf16x8 pack8(f32x4 a, f32x4 b) {
  bf16x8 r;
  r[0] = (__bf16)a[0]; r[1] = (__bf16)a[1]; r[2] = (__bf16)a[2]; r[3] = (__bf16)a[3];
  r[4] = (__bf16)b[0]; r[5] = (__bf16)b[1]; r[6] = (__bf16)b[2]; r[7] = (__bf16)b[3];
  return r;
}

// ---------------------------------------------------------------------------
// Kernel 1: per-node precompute, SLOT-PERMUTED output layout.
//   logical P[n][h] (h = nt*16 + lrow) stored at pq[n*128 + 4*lrow + nt]
//   logical Q[n][h]                  at pq[n*128 + 64 + 4*lrow + nt]
// so the edge kernel reads one lane's 4 values as a single 8B load.
// ---------------------------------------------------------------------------
__global__ __launch_bounds__(256, 2)
void pq_kernel(const float* __restrict__ x, const float* __restrict__ W1,
               __bf16* __restrict__ pq, int n_nodes)
{
  __shared__ __align__(16) __bf16 xbf[64 * 128];
  __shared__ __align__(16) __bf16 wab[128 * 128];

  const int tid  = threadIdx.x;
  const int lane = tid & 63;
  const int w    = tid >> 6;
  const int base = blockIdx.x * 64;

  for (int i = tid; i < 128 * 16; i += 256) {
    int row = i >> 4, blk = i & 15;
    const float* src = W1 + (row & 63) * 384 + ((row >> 6) << 7) + blk * 8;
    *(bf16x8*)&wab[row * 128 + swz(row, blk * 8)] = cvt8(src);
  }
  for (int i = tid; i < 64 * 16; i += 256) {
    int row = i >> 4, blk = i & 15;
    int node = base + row; if (node >= n_nodes) node = 0;
    *(bf16x8*)&xbf[row * 128 + swz(row, blk * 8)] = cvt8(x + (size_t)node * 128 + blk * 8);
  }
  __syncthreads();

  const int lrow = lane & 15;
  const int lkb  = (lane >> 4) << 3;

  f32x4 acc[8] = {};
#pragma unroll
  for (int kk = 0; kk < 4; ++kk) {
    int k = kk * 32 + lkb;
    int arow = w * 16 + lrow;
    bf16x8 a = *(bf16x8*)&xbf[arow * 128 + swz(arow, k)];
#pragma unroll
    for (int nt = 0; nt < 8; ++nt) {
      int brow = nt * 16 + lrow;
      bf16x8 b = *(bf16x8*)&wab[brow * 128 + swz(brow, k)];
      acc[nt] = __builtin_amdgcn_mfma_f32_16x16x32_bf16(a, b, acc[nt], 0, 0, 0);
    }
  }

  // D: col h16 = nt*16 + lrow, row = w*16 + (lane>>4)*4 + r
#pragma unroll
  for (int r = 0; r < 4; ++r) {
    int nrow = base + w * 16 + ((lane >> 4) << 2) + r;
    if (nrow < n_nodes) {
      bf16x4 vp, vq;
#pragma unroll
      for (int j = 0; j < 4; ++j) { vp[j] = (__bf16)acc[j][r]; vq[j] = (__bf16)acc[4 + j][r]; }
      *(bf16x4*)&pq[(size_t)nrow * 128 + 4 * lrow]      = vp;
      *(bf16x4*)&pq[(size_t)nrow * 128 + 64 + 4 * lrow] = vq;
    }
  }
}

// ---------------------------------------------------------------------------
// Kernel 2: fused edge MLP. Wave-independent 16-edge tiles, depth-2 software
// pipeline on the e-stream, depth-2 on ei, depth-1 on the 8B slot-permuted pq
// gathers. launch_bounds(256,3): 3 blocks/CU (R4 A/B: 2 blocks/CU -> 145us,
// latency not fully hidden at 2 waves/SIMD; VGPR cap 168 is the tradeoff).
// ---------------------------------------------------------------------------
__global__ __launch_bounds__(256, 3)
void edge_kernel(const int* __restrict__ ei, const float* __restrict__ e,
                 const __bf16* __restrict__ pq,
                 const float* __restrict__ W1, const float* __restrict__ b1,
                 const float* __restrict__ W2, const float* __restrict__ b2,
                 const float* __restrict__ W3, const float* __restrict__ b3,
                 float* __restrict__ out, int E, int ntw, int nwaves)
{
  __shared__ __align__(16) __bf16 wc [64 * 128];    // W1c rows [h][k], swizzled
  __shared__ __align__(16) __bf16 w2l[64 * 64];     // W2 rows  [h][k], swizzled
  __shared__ __align__(16) __bf16 h1l[4 * 16 * 64]; // per-wave h1 [16][64], swizzled

  const int tid  = threadIdx.x;
  const int lane = tid & 63;
  const int w    = tid >> 6;
  const int lrow = lane & 15;
  const int hi   = lane >> 4;
  const int hi8  = hi << 3;

  for (int i = tid; i < 64 * 16; i += 256) {
    int row = i >> 4, blk = i & 15;
    *(bf16x8*)&wc[row * 128 + swz(row, blk * 8)] = cvt8(W1 + row * 384 + 256 + blk * 8);
  }
  for (int i = tid; i < 64 * 8; i += 256) {
    int row = i >> 3, blk = i & 7;
    *(bf16x8*)&w2l[row * 64 + swz(row, blk * 8)] = cvt8(W2 + row * 64 + blk * 8);
  }
  __syncthreads();

  float b1f[4], b2f[4], w3f[4];
#pragma unroll
  for (int nt = 0; nt < 4; ++nt) {
    b1f[nt] = b1[nt * 16 + lrow];
    b2f[nt] = b2[nt * 16 + lrow];
    w3f[nt] = W3[nt * 16 + lrow];
  }
  const float b3v = b3[0];

  __bf16* h1w = &h1l[w * 16 * 64];

  const int g  = blockIdx.x * 4 + w;
  const int q  = ntw / nwaves, rmd = ntw % nwaves;
  const int t0 = g * q + (g < rmd ? g : rmd);
  const int t1 = t0 + q + (g < rmd ? 1 : 0);
  if (t0 >= t1) return;
  const int tlast = t1 - 1;

  auto clampT = [&](int t) { return t > tlast ? tlast : t; };

  auto issue_e = [&](int t, f32x4 (&er)[8]) {
    int row = t * 16 + lrow; if (row >= E) row = E - 1;
    const float* ep = e + (size_t)row * 128 + hi8;
#pragma unroll
    for (int kk = 0; kk < 4; ++kk) {
      er[2 * kk]     = *(const f32x4*)(ep + kk * 32);
      er[2 * kk + 1] = *(const f32x4*)(ep + kk * 32 + 4);
    }
  };

  auto issue_ei = [&](int t, i32x4& sv, i32x4& dv) {
    int eb = t * 16 + hi * 4;
    if (eb + 3 < E) {
      sv = *(const i32x4*)(ei + eb);
      dv = *(const i32x4*)(ei + E + eb);
    } else {
#pragma unroll
      for (int r = 0; r < 4; ++r) {
        int rr = eb + r; if (rr >= E) rr = E - 1;
        sv[r] = ei[rr]; dv[r] = ei[E + rr];
      }
    }
  };

  // 8B gathers: lane's 4 pre values per endpoint are contiguous (slot-permuted pq)
  auto issue_pq = [&](const i32x4& sv, const i32x4& dv,
                      bf16x4 (&ps)[4], bf16x4 (&pd)[4]) {
#pragma unroll
    for (int r = 0; r < 4; ++r) {
      ps[r] = *(const bf16x4*)(pq + (size_t)sv[r] * 128 + 4 * lrow);
      pd[r] = *(const bf16x4*)(pq + (size_t)dv[r] * 128 + 64 + 4 * lrow);
    }
  };

  auto pack_all = [&](const f32x4 (&ef)[8], bf16x8 (&a)[4]) {
#pragma unroll
    for (int kk = 0; kk < 4; ++kk) a[kk] = pack8(ef[2 * kk], ef[2 * kk + 1]);
  };

  auto body = [&](int t, f32x4 (&eIss)[8], f32x4 (&ePack)[8],
                  bf16x8 (&aC)[4], i32x4& svU, i32x4& dvU,
                  bf16x4 (&psC)[4], bf16x4 (&pdC)[4],
                  bf16x4 (&psN)[4], bf16x4 (&pdN)[4]) {
    const int ebase = t * 16;

    issue_e(clampT(t + 2), eIss);

    // layer 1: A from aC (ready), B from LDS
    f32x4 acc1[4] = {};
#pragma unroll
    for (int kk = 0; kk < 4; ++kk) {
      int k = kk * 32 + hi8;
#pragma unroll
      for (int nt = 0; nt < 4; ++nt) {
        int brow = nt * 16 + lrow;
        bf16x8 b = *(bf16x8*)&wc[brow * 128 + swz(brow, k)];
        acc1[nt] = __builtin_amdgcn_mfma_f32_16x16x32_bf16(aC[kk], b, acc1[nt], 0, 0, 0);
      }
    }

    issue_pq(svU, dvU, psN, pdN);          // pre for t+1 (ei arrived 2 bodies ago)
    issue_ei(clampT(t + 3), svU, dvU);     // refill after addresses consumed

    // epilogue 1: relu(acc1 + b1 + P_src + Q_dst) -> bf16 wave-private LDS
#pragma unroll
    for (int nt = 0; nt < 4; ++nt) {
#pragma unroll
      for (int r = 0; r < 4; ++r) {
        int row = hi * 4 + r;
        int h   = nt * 16 + lrow;
        float v = acc1[nt][r] + b1f[nt] + (float)psC[r][nt] + (float)pdC[r][nt];
        v = v > 0.f ? v : 0.f;
        h1w[row * 64 + swz(row, h)] = (__bf16)v;
      }
    }

    // layer 2
    f32x4 acc2[4] = {};
#pragma unroll
    for (int ks = 0; ks < 2; ++ks) {
      int k = ks * 32 + hi8;
      bf16x8 a = *(bf16x8*)&h1w[lrow * 64 + swz(lrow, k)];
#pragma unroll
      for (int nt = 0; nt < 4; ++nt) {
        int brow = nt * 16 + lrow;
        bf16x8 b = *(bf16x8*)&w2l[brow * 64 + swz(brow, k)];
        acc2[nt] = __builtin_amdgcn_mfma_f32_16x16x32_bf16(a, b, acc2[nt], 0, 0, 0);
      }
    }

    // epilogue 2 + layer 3
    float part[4] = {0.f, 0.f, 0.f, 0.f};
#pragma unroll
    for (int nt = 0; nt < 4; ++nt) {
#pragma unroll
      for (int r = 0; r < 4; ++r) {
        float v = acc2[nt][r] + b2f[nt];
        v = v > 0.f ? v : 0.f;
        part[r] += v * w3f[nt];
      }
    }
#pragma unroll
    for (int m = 1; m < 16; m <<= 1) {
#pragma unroll
      for (int r = 0; r < 4; ++r) part[r] += __shfl_xor(part[r], m, 64);
    }
    if (lrow == 0) {
      int obase = ebase + hi * 4;
      if (obase + 3 < E) {
        f32x4 v; v[0] = part[0] + b3v; v[1] = part[1] + b3v;
        v[2] = part[2] + b3v; v[3] = part[3] + b3v;
        *(f32x4*)(out + obase) = v;
      } else {
#pragma unroll
        for (int r = 0; r < 4; ++r)
          if (obase + r < E) out[obase + r] = part[r] + b3v;
      }
    }

    pack_all(ePack, aC);   // t+1 arrived (issued 2 bodies ago); frees ePack
  };

  // ---- prologue ----
  f32x4 eF0[8], eF1[8];
  bf16x8 aC[4];
  i32x4 svA, dvA, svB, dvB, svT, dvT;
  bf16x4 psA[4], pdA[4], psB[4], pdB[4];

  issue_ei(t0, svT, dvT);
  issue_ei(clampT(t0 + 1), svA, dvA);
  issue_ei(clampT(t0 + 2), svB, dvB);
  issue_e(t0, eF1);
  issue_e(clampT(t0 + 1), eF0);
  issue_pq(svT, dvT, psA, pdA);   // pre(t0)
  pack_all(eF1, aC);              // waits e(t0); eF1 now free

  // ---- main loop: 2x-unrolled rotation ----
  int t = t0;
  for (; t + 1 < t1; t += 2) {
    body(t,     eF1, eF0, aC, svA, dvA, psA, pdA, psB, pdB);
    body(t + 1, eF0, eF1, aC, svB, dvB, psB, pdB, psA, pdA);
  }
  if (t < t1)
    body(t, eF1, eF0, aC, svA, dvA, psA, pdA, psB, pdB);
}

// ---------------------------------------------------------------------------
// Exact f32 fallback (only if ws too small)
// ---------------------------------------------------------------------------
__global__ void naive_kernel(const int* __restrict__ ei, const float* __restrict__ x,
                             const float* __restrict__ e,
                             const float* __restrict__ W1, const float* __restrict__ b1,
                             const float* __restrict__ W2, const float* __restrict__ b2,
                             const float* __restrict__ W3, const float* __restrict__ b3,
                             float* __restrict__ out, int E)
{
  __shared__ float h1[64];
  int edge = blockIdx.x;
  int h = threadIdx.x;
  int s = ei[edge], d = ei[E + edge];
  const float* w1r = W1 + h * 384;
  float acc = b1[h];
  for (int k = 0; k < 128; ++k) acc += w1r[k]       * x[(size_t)s * 128 + k];
  for (int k = 0; k < 128; ++k) acc += w1r[128 + k] * x[(size_t)d * 128 + k];
  for (int k = 0; k < 128; ++k) acc += w1r[256 + k] * e[(size_t)edge * 128 + k];
  h1[h] = acc > 0.f ? acc : 0.f;
  __syncthreads();
  float acc2 = b2[h];
  for (int k = 0; k < 64; ++k) acc2 += W2[h * 64 + k] * h1[k];
  acc2 = acc2 > 0.f ? acc2 : 0.f;
  float p = acc2 * W3[h];
  for (int m = 1; m < 64; m <<= 1) p += __shfl_xor(p, m, 64);
  if (h == 0) out[edge] = p + b3[0];
}

extern "C" void kernel_launch(void* const* d_in, const int* in_sizes, int n_in,
                              void* d_out, int out_size, void* d_ws, size_t ws_size,
                              hipStream_t stream) {
  const int*   ei = (const int*)d_in[0];
  const float* x  = (const float*)d_in[1];
  const float* e  = (const float*)d_in[2];
  const float* W1 = (const float*)d_in[3];
  const float* b1 = (const float*)d_in[4];
  const float* W2 = (const float*)d_in[5];
  const float* b2 = (const float*)d_in[6];
  const float* W3 = (const float*)d_in[7];
  const float* b3 = (const float*)d_in[8];
  float* out = (float*)d_out;

  const int E = in_sizes[0] / 2;
  const int N = in_sizes[1] / 128;

  const size_t need = (size_t)N * 128 * sizeof(__bf16);
  if (ws_size < need) {
    naive_kernel<<<E, 64, 0, stream>>>(ei, x, e, W1, b1, W2, b2, W3, b3, out, E);
    return;
  }

  __bf16* pq = (__bf16*)d_ws;
  const int nwg = (N + 63) / 64;
  pq_kernel<<<nwg, 256, 0, stream>>>(x, W1, pq, N);

  const int ntw    = (E + 15) / 16;   // 16-edge wave-tiles
  const int nblk   = 768;             // 3 blocks/CU (VGPR cap 168)
  const int nwaves = nblk * 4;
  edge_kernel<<<nblk, 256, 0, stream>>>(ei, e, pq, W1, b1, W2, b2, W3, b3,
                                        out, E, ntw, nwaves);
}

// Round 6
// 151.955 us; speedup vs baseline: 1.7738x; 1.7738x over previous
//
#include <hip/hip_runtime.h>

typedef float f32x4 __attribute__((ext_vector_type(4)));
typedef __bf16 bf16x8 __attribute__((ext_vector_type(8)));
typedef __bf16 bf16x4 __attribute__((ext_vector_type(4)));
typedef int i32x4 __attribute__((ext_vector_type(4)));

// XOR swizzle in elements (2B): byte ^= ((row&7)<<4)  ->  elem col ^= ((row&7)<<3)
__device__ __forceinline__ int swz(int row, int col) {
  return col ^ ((row & 7) << 3);
}

__device__ __forceinline__ bf16x8 cvt8(const float* __restrict__ src) {
  f32x4 a = *(const f32x4*)src;
  f32x4 b = *(const f32x4*)(src + 4);
  bf16x8 r;
  r[0] = (__bf16)a[0]; r[1] = (__bf16)a[1]; r[2] = (__bf16)a[2]; r[3] = (__bf16)a[3];
  r[4] = (__bf16)b[0]; r[5] = (__bf16)b[1]; r[6] = (__bf16)b[2]; r[7] = (__bf16)b[3];
  return r;
}

__device__ __forceinline__ bf16x8 pack8(f32x4 a, f32x4 b) {
  bf16x8 r;
  r[0] = (__bf16)a[0]; r[1] = (__bf16)a[1]; r[2] = (__bf16)a[2]; r[3] = (__bf16)a[3];
  r[4] = (__bf16)b[0]; r[5] = (__bf16)b[1]; r[6] = (__bf16)b[2]; r[7] = (__bf16)b[3];
  return r;
}

// ---------------------------------------------------------------------------
// Kernel 1: per-node precompute, SLOT-PERMUTED output layout.
//   logical P[n][h] (h = nt*16 + lrow) stored at pq[n*128 + 4*lrow + nt]
//   logical Q[n][h]                  at pq[n*128 + 64 + 4*lrow + nt]
// so the edge kernel reads one lane's 4 values as a single 8B load.
// ---------------------------------------------------------------------------
__global__ __launch_bounds__(256, 2)
void pq_kernel(const float* __restrict__ x, const float* __restrict__ W1,
               __bf16* __restrict__ pq, int n_nodes)
{
  __shared__ __align__(16) __bf16 xbf[64 * 128];
  __shared__ __align__(16) __bf16 wab[128 * 128];

  const int tid  = threadIdx.x;
  const int lane = tid & 63;
  const int w    = tid >> 6;
  const int base = blockIdx.x * 64;

  for (int i = tid; i < 128 * 16; i += 256) {
    int row = i >> 4, blk = i & 15;
    const float* src = W1 + (row & 63) * 384 + ((row >> 6) << 7) + blk * 8;
    *(bf16x8*)&wab[row * 128 + swz(row, blk * 8)] = cvt8(src);
  }
  for (int i = tid; i < 64 * 16; i += 256) {
    int row = i >> 4, blk = i & 15;
    int node = base + row; if (node >= n_nodes) node = 0;
    *(bf16x8*)&xbf[row * 128 + swz(row, blk * 8)] = cvt8(x + (size_t)node * 128 + blk * 8);
  }
  __syncthreads();

  const int lrow = lane & 15;
  const int lkb  = (lane >> 4) << 3;

  f32x4 acc[8] = {};
#pragma unroll
  for (int kk = 0; kk < 4; ++kk) {
    int k = kk * 32 + lkb;
    int arow = w * 16 + lrow;
    bf16x8 a = *(bf16x8*)&xbf[arow * 128 + swz(arow, k)];
#pragma unroll
    for (int nt = 0; nt < 8; ++nt) {
      int brow = nt * 16 + lrow;
      bf16x8 b = *(bf16x8*)&wab[brow * 128 + swz(brow, k)];
      acc[nt] = __builtin_amdgcn_mfma_f32_16x16x32_bf16(a, b, acc[nt], 0, 0, 0);
    }
  }

#pragma unroll
  for (int r = 0; r < 4; ++r) {
    int nrow = base + w * 16 + ((lane >> 4) << 2) + r;
    if (nrow < n_nodes) {
      bf16x4 vp, vq;
#pragma unroll
      for (int j = 0; j < 4; ++j) { vp[j] = (__bf16)acc[j][r]; vq[j] = (__bf16)acc[4 + j][r]; }
      *(bf16x4*)&pq[(size_t)nrow * 128 + 4 * lrow]      = vp;
      *(bf16x4*)&pq[(size_t)nrow * 128 + 64 + 4 * lrow] = vq;
    }
  }
}

// ---------------------------------------------------------------------------
// Kernel 2: fused edge MLP. Wave-independent 16-edge tiles, SLIM depth-1
// pipeline: single f32 e-buffer (issue t+1 at body start, pack at body end),
// one ei pair (consume-then-refill), depth-1 pq gathers. Peak live ~150-165
// VGPR so launch_bounds(256,3) fits WITHOUT spilling (R5 lesson: capping a
// ~190-reg structure at 168 spilled and cost 1.7x).
// ---------------------------------------------------------------------------
__global__ __launch_bounds__(256, 3)
void edge_kernel(const int* __restrict__ ei, const float* __restrict__ e,
                 const __bf16* __restrict__ pq,
                 const float* __restrict__ W1, const float* __restrict__ b1,
                 const float* __restrict__ W2, const float* __restrict__ b2,
                 const float* __restrict__ W3, const float* __restrict__ b3,
                 float* __restrict__ out, int E, int ntw, int nwaves)
{
  __shared__ __align__(16) __bf16 wc [64 * 128];    // W1c rows [h][k], swizzled
  __shared__ __align__(16) __bf16 w2l[64 * 64];     // W2 rows  [h][k], swizzled
  __shared__ __align__(16) __bf16 h1l[4 * 16 * 64]; // per-wave h1 [16][64], swizzled

  const int tid  = threadIdx.x;
  const int lane = tid & 63;
  const int w    = tid >> 6;
  const int lrow = lane & 15;
  const int hi   = lane >> 4;
  const int hi8  = hi << 3;

  for (int i = tid; i < 64 * 16; i += 256) {
    int row = i >> 4, blk = i & 15;
    *(bf16x8*)&wc[row * 128 + swz(row, blk * 8)] = cvt8(W1 + row * 384 + 256 + blk * 8);
  }
  for (int i = tid; i < 64 * 8; i += 256) {
    int row = i >> 3, blk = i & 7;
    *(bf16x8*)&w2l[row * 64 + swz(row, blk * 8)] = cvt8(W2 + row * 64 + blk * 8);
  }
  __syncthreads();

  float b1f[4], b2f[4], w3f[4];
#pragma unroll
  for (int nt = 0; nt < 4; ++nt) {
    b1f[nt] = b1[nt * 16 + lrow];
    b2f[nt] = b2[nt * 16 + lrow];
    w3f[nt] = W3[nt * 16 + lrow];
  }
  const float b3v = b3[0];

  __bf16* h1w = &h1l[w * 16 * 64];

  const int g  = blockIdx.x * 4 + w;
  const int q  = ntw / nwaves, rmd = ntw % nwaves;
  const int t0 = g * q + (g < rmd ? g : rmd);
  const int t1 = t0 + q + (g < rmd ? 1 : 0);
  if (t0 >= t1) return;
  const int tlast = t1 - 1;

  auto clampT = [&](int t) { return t > tlast ? tlast : t; };

  auto issue_e = [&](int t, f32x4 (&er)[8]) {
    int row = t * 16 + lrow; if (row >= E) row = E - 1;
    const float* ep = e + (size_t)row * 128 + hi8;
#pragma unroll
    for (int kk = 0; kk < 4; ++kk) {
      er[2 * kk]     = *(const f32x4*)(ep + kk * 32);
      er[2 * kk + 1] = *(const f32x4*)(ep + kk * 32 + 4);
    }
  };

  auto issue_ei = [&](int t, i32x4& sv, i32x4& dv) {
    int eb = t * 16 + hi * 4;
    if (eb + 3 < E) {
      sv = *(const i32x4*)(ei + eb);
      dv = *(const i32x4*)(ei + E + eb);
    } else {
#pragma unroll
      for (int r = 0; r < 4; ++r) {
        int rr = eb + r; if (rr >= E) rr = E - 1;
        sv[r] = ei[rr]; dv[r] = ei[E + rr];
      }
    }
  };

  // 8B gathers: lane's 4 pre values per endpoint are contiguous (slot-permuted pq)
  auto issue_pq = [&](const i32x4& sv, const i32x4& dv,
                      bf16x4 (&ps)[4], bf16x4 (&pd)[4]) {
#pragma unroll
    for (int r = 0; r < 4; ++r) {
      ps[r] = *(const bf16x4*)(pq + (size_t)sv[r] * 128 + 4 * lrow);
      pd[r] = *(const bf16x4*)(pq + (size_t)dv[r] * 128 + 64 + 4 * lrow);
    }
  };

  auto pack_all = [&](const f32x4 (&ef)[8], bf16x8 (&a)[4]) {
#pragma unroll
    for (int kk = 0; kk < 4; ++kk) a[kk] = pack8(ef[2 * kk], ef[2 * kk + 1]);
  };

  // body(t): aC holds packed e(t); eF receives e(t+1) (packed at body end);
  // svU/dvU hold ei(t+1) on entry -> used for pq(t+1), then refilled ei(t+2);
  // psC/pdC = pre(t) consumed; psN/pdN = pre(t+1) issued.
  auto body = [&](int t, f32x4 (&eF)[8], bf16x8 (&aC)[4],
                  i32x4& svU, i32x4& dvU,
                  bf16x4 (&psC)[4], bf16x4 (&pdC)[4],
                  bf16x4 (&psN)[4], bf16x4 (&pdN)[4]) {
    const int ebase = t * 16;

    issue_e(clampT(t + 1), eF);

    // layer 1: A from aC (ready), B from LDS
    f32x4 acc1[4] = {};
#pragma unroll
    for (int kk = 0; kk < 4; ++kk) {
      int k = kk * 32 + hi8;
#pragma unroll
      for (int nt = 0; nt < 4; ++nt) {
        int brow = nt * 16 + lrow;
        bf16x8 b = *(bf16x8*)&wc[brow * 128 + swz(brow, k)];
        acc1[nt] = __builtin_amdgcn_mfma_f32_16x16x32_bf16(aC[kk], b, acc1[nt], 0, 0, 0);
      }
    }

    issue_pq(svU, dvU, psN, pdN);          // pre(t+1); ei(t+1) arrived 1 body ago
    issue_ei(clampT(t + 2), svU, dvU);     // refill same regs with ei(t+2)

    // epilogue 1: relu(acc1 + b1 + P_src + Q_dst) -> bf16 wave-private LDS
#pragma unroll
    for (int nt = 0; nt < 4; ++nt) {
#pragma unroll
      for (int r = 0; r < 4; ++r) {
        int row = hi * 4 + r;
        int h   = nt * 16 + lrow;
        float v = acc1[nt][r] + b1f[nt] + (float)psC[r][nt] + (float)pdC[r][nt];
        v = v > 0.f ? v : 0.f;
        h1w[row * 64 + swz(row, h)] = (__bf16)v;
      }
    }

    // layer 2
    f32x4 acc2[4] = {};
#pragma unroll
    for (int ks = 0; ks < 2; ++ks) {
      int k = ks * 32 + hi8;
      bf16x8 a = *(bf16x8*)&h1w[lrow * 64 + swz(lrow, k)];
#pragma unroll
      for (int nt = 0; nt < 4; ++nt) {
        int brow = nt * 16 + lrow;
        bf16x8 b = *(bf16x8*)&w2l[brow * 64 + swz(brow, k)];
        acc2[nt] = __builtin_amdgcn_mfma_f32_16x16x32_bf16(a, b, acc2[nt], 0, 0, 0);
      }
    }

    // epilogue 2 + layer 3
    float part[4] = {0.f, 0.f, 0.f, 0.f};
#pragma unroll
    for (int nt = 0; nt < 4; ++nt) {
#pragma unroll
      for (int r = 0; r < 4; ++r) {
        float v = acc2[nt][r] + b2f[nt];
        v = v > 0.f ? v : 0.f;
        part[r] += v * w3f[nt];
      }
    }
#pragma unroll
    for (int m = 1; m < 16; m <<= 1) {
#pragma unroll
      for (int r = 0; r < 4; ++r) part[r] += __shfl_xor(part[r], m, 64);
    }
    if (lrow == 0) {
      int obase = ebase + hi * 4;
      if (obase + 3 < E) {
        f32x4 v; v[0] = part[0] + b3v; v[1] = part[1] + b3v;
        v[2] = part[2] + b3v; v[3] = part[3] + b3v;
        *(f32x4*)(out + obase) = v;
      } else {
#pragma unroll
        for (int r = 0; r < 4; ++r)
          if (obase + r < E) out[obase + r] = part[r] + b3v;
      }
    }

    pack_all(eF, aC);   // e(t+1) arrived (issued a body ago); frees eF
  };

  // ---- prologue ----
  f32x4 eF[8];
  bf16x8 aC[4];
  i32x4 svU, dvU;
  bf16x4 psA[4], pdA[4], psB[4], pdB[4];

  issue_ei(t0, svU, dvU);              // ei(t0)
  issue_e(t0, eF);                     // e(t0)
  issue_pq(svU, dvU, psA, pdA);        // pre(t0)
  issue_ei(clampT(t0 + 1), svU, dvU);  // ei(t0+1)
  pack_all(eF, aC);                    // waits e(t0)

  // ---- main loop: 2x-unrolled A/B rotation of the pre buffers ----
  int t = t0;
  for (; t + 1 < t1; t += 2) {
    body(t,     eF, aC, svU, dvU, psA, pdA, psB, pdB);
    body(t + 1, eF, aC, svU, dvU, psB, pdB, psA, pdA);
  }
  if (t < t1)
    body(t, eF, aC, svU, dvU, psA, pdA, psB, pdB);
}

// ---------------------------------------------------------------------------
// Exact f32 fallback (only if ws too small)
// ---------------------------------------------------------------------------
__global__ void naive_kernel(const int* __restrict__ ei, const float* __restrict__ x,
                             const float* __restrict__ e,
                             const float* __restrict__ W1, const float* __restrict__ b1,
                             const float* __restrict__ W2, const float* __restrict__ b2,
                             const float* __restrict__ W3, const float* __restrict__ b3,
                             float* __restrict__ out, int E)
{
  __shared__ float h1[64];
  int edge = blockIdx.x;
  int h = threadIdx.x;
  int s = ei[edge], d = ei[E + edge];
  const float* w1r = W1 + h * 384;
  float acc = b1[h];
  for (int k = 0; k < 128; ++k) acc += w1r[k]       * x[(size_t)s * 128 + k];
  for (int k = 0; k < 128; ++k) acc += w1r[128 + k] * x[(size_t)d * 128 + k];
  for (int k = 0; k < 128; ++k) acc += w1r[256 + k] * e[(size_t)edge * 128 + k];
  h1[h] = acc > 0.f ? acc : 0.f;
  __syncthreads();
  float acc2 = b2[h];
  for (int k = 0; k < 64; ++k) acc2 += W2[h * 64 + k] * h1[k];
  acc2 = acc2 > 0.f ? acc2 : 0.f;
  float p = acc2 * W3[h];
  for (int m = 1; m < 64; m <<= 1) p += __shfl_xor(p, m, 64);
  if (h == 0) out[edge] = p + b3[0];
}

extern "C" void kernel_launch(void* const* d_in, const int* in_sizes, int n_in,
                              void* d_out, int out_size, void* d_ws, size_t ws_size,
                              hipStream_t stream) {
  const int*   ei = (const int*)d_in[0];
  const float* x  = (const float*)d_in[1];
  const float* e  = (const float*)d_in[2];
  const float* W1 = (const float*)d_in[3];
  const float* b1 = (const float*)d_in[4];
  const float* W2 = (const float*)d_in[5];
  const float* b2 = (const float*)d_in[6];
  const float* W3 = (const float*)d_in[7];
  const float* b3 = (const float*)d_in[8];
  float* out = (float*)d_out;

  const int E = in_sizes[0] / 2;
  const int N = in_sizes[1] / 128;

  const size_t need = (size_t)N * 128 * sizeof(__bf16);
  if (ws_size < need) {
    naive_kernel<<<E, 64, 0, stream>>>(ei, x, e, W1, b1, W2, b2, W3, b3, out, E);
    return;
  }

  __bf16* pq = (__bf16*)d_ws;
  const int nwg = (N + 63) / 64;
  pq_kernel<<<nwg, 256, 0, stream>>>(x, W1, pq, N);

  const int ntw    = (E + 15) / 16;   // 16-edge wave-tiles
  const int nblk   = 768;             // 3 blocks/CU (slim regs, no cap-spill)
  const int nwaves = nblk * 4;
  edge_kernel<<<nblk, 256, 0, stream>>>(ei, e, pq, W1, b1, W2, b2, W3, b3,
                                        out, E, ntw, nwaves);
}